// Round 9
// baseline (125.841 us; speedup 1.0000x reference)
//
#include <hip/hip_runtime.h>

// B=16, C=128, H=W=64, N=4096 (zigzag p-space), M=1024, CQ=16, CV=64.
// ws (shorts): qT[16][4096][16] @0, kT[16][1024][16] @1048576,
//              vT[16][32 mt][2 ks][64 c2][16 mm] @1310720.  Total 4.7 MB.

#define LOG2E 1.4426950408889634f

typedef __attribute__((ext_vector_type(8)))  short bf16x8;
typedef __attribute__((ext_vector_type(16))) float f32x16;
typedef unsigned long long ull;

static __device__ __forceinline__ unsigned cvt_pk_bf16(float a, float b) {
  unsigned r;
  asm("v_cvt_pk_bf16_f32 %0, %1, %2" : "=v"(r) : "v"(a), "v"(b));
  return r;
}
static __device__ __forceinline__ void perm32swap(unsigned& a, unsigned& b) {
  asm volatile("v_permlane32_swap_b32 %0, %1" : "+v"(a), "+v"(b));
}
static __device__ __forceinline__ float fexp2(float x) {
  float r; asm("v_exp_f32 %0, %1" : "=v"(r) : "v"(x)); return r;
}
static __device__ __forceinline__ bf16x8 pack4(unsigned u0, unsigned u1,
                                               unsigned u2, unsigned u3) {
  union { bf16x8 v; unsigned u[4]; } r;
  r.u[0] = u0; r.u[1] = u1; r.u[2] = u2; r.u[3] = u3;
  return r.v;
}
static __device__ __forceinline__ bf16x8 pack2ull(ull a, ull b) {
  union { bf16x8 v; ull u[2]; } r;
  r.u[0] = a; r.u[1] = b;
  return r.v;
}
static __device__ __forceinline__ short f2bf(float f) {   // RTNE
  unsigned u = __float_as_uint(f);
  u = (u + 0x7FFFu + ((u >> 16) & 1u)) >> 16;
  return (short)u;
}
// bijective LDS column swizzle for proj x_s
static __device__ __forceinline__ int swzj(int j) {
  return j ^ ((j >> 2) & 7) ^ (((j >> 6) & 1) << 2);
}
#define FK(V, K) ((K) == 0 ? (V).x : (K) == 1 ? (V).y : (K) == 2 ? (V).z : (V).w)

// ---------------------------------------------------------------------------
// Kernel 1: fused transpose + q/k/v proj + pool. R8 structure with 2-pass
// x_s (16 KB halves): both x load batches issued up front, batch1 held in
// registers through phase-1 MFMA (T14 overlap).
// ---------------------------------------------------------------------------
#define WSTRIDE 136   // shorts; 272B row stride, 16B-aligned frag reads

__global__ __launch_bounds__(256) void proj_kernel(
    const float* __restrict__ x, const float* __restrict__ wq,
    const float* __restrict__ wk, const float* __restrict__ wv,
    short* __restrict__ qT, short* __restrict__ kT, short* __restrict__ vT)
{
  __shared__ short x_s[8 * 1024];       // 16 KB: [g][swz(j)][8c] (one c-half)
  __shared__ short w_s[96 * WSTRIDE];   // 25.5 KB
  __shared__ short v_s[2048];           // 4 KB: [ks][c2][16 mm]

  const int b = blockIdx.y, t = threadIdx.x;
  const int wid = t >> 6, lane = t & 63;
  const int l31 = lane & 31, hi = lane >> 5;
  const int r = blockIdx.x;             // pooled row 0..31 == m-tile index
  const float* xb = x + (size_t)b * 128 * 4096 + r * 128;

  // ---- issue ALL x loads up front (2 batches of 8 float4) ----
  const int j4  = (t & 31) * 4;
  const int c00 = (t >> 5) * 8;
  float4 f0_[8], f1_[8];
  #pragma unroll
  for (int i = 0; i < 8; ++i)
    f0_[i] = *(const float4*)(xb + (size_t)(c00 + i) * 4096 + j4);
  #pragma unroll
  for (int i = 0; i < 8; ++i)
    f1_[i] = *(const float4*)(xb + (size_t)(c00 + i + 64) * 4096 + j4);

  // ---- stage weights -> LDS ----
  #pragma unroll
  for (int kk = 0; kk < 12; ++kk) {
    const int idx = t + kk * 256;          // 0..3071
    const int row = idx >> 5, c4 = (idx & 31) << 2;
    const float* src = (row < 16) ? (wq + row * 128 + c4)
                     : (row < 32) ? (wk + (row - 16) * 128 + c4)
                                  : (wv + (row - 32) * 128 + c4);
    const float4 f = *(const float4*)src;
    const ull v = ((ull)cvt_pk_bf16(f.z, f.w) << 32) | (ull)cvt_pk_bf16(f.x, f.y);
    *(ull*)&w_s[row * WSTRIDE + c4] = v;
  }

  // ---- pack + write batch0 (c 0..63) ----
  const int g = t >> 5;
  #pragma unroll
  for (int k = 0; k < 4; ++k) {
    const bf16x8 frag = pack4(
        cvt_pk_bf16(FK(f0_[0], k), FK(f0_[1], k)),
        cvt_pk_bf16(FK(f0_[2], k), FK(f0_[3], k)),
        cvt_pk_bf16(FK(f0_[4], k), FK(f0_[5], k)),
        cvt_pk_bf16(FK(f0_[6], k), FK(f0_[7], k)));
    *(bf16x8*)&x_s[g * 1024 + swzj(j4 + k) * 8] = frag;
  }
  __syncthreads();

  // ---- per-lane position (zigzag within the pooled row) ----
  const int p_local = wid * 32 + l31;
  const int q2l = p_local >> 2, rr = p_local & 3;
  const int jl = (rr >> 1) * 64 + q2l * 2 + (rr & 1);   // local n
  const int p = r * 128 + p_local;                      // global zigzag p

  f32x16 acc0, acc1, acc2;
  #pragma unroll
  for (int j = 0; j < 16; ++j) { acc0[j] = 0.f; acc1[j] = 0.f; acc2[j] = 0.f; }

  // ---- phase 1: c 0..63 ----
  #pragma unroll
  for (int cc = 0; cc < 4; ++cc) {
    const bf16x8 xf = *(const bf16x8*)&x_s[(cc * 2 + hi) * 1024 + swzj(jl) * 8];
    const int off = cc * 16 + hi * 8;
    const bf16x8 a0 = *(const bf16x8*)&w_s[l31 * WSTRIDE + off];
    const bf16x8 a1 = *(const bf16x8*)&w_s[(32 + l31) * WSTRIDE + off];
    const bf16x8 a2 = *(const bf16x8*)&w_s[(64 + l31) * WSTRIDE + off];
    acc0 = __builtin_amdgcn_mfma_f32_32x32x16_bf16(a0, xf, acc0, 0, 0, 0);
    acc1 = __builtin_amdgcn_mfma_f32_32x32x16_bf16(a1, xf, acc1, 0, 0, 0);
    acc2 = __builtin_amdgcn_mfma_f32_32x32x16_bf16(a2, xf, acc2, 0, 0, 0);
  }
  __syncthreads();

  // ---- write batch1 (c 64..127) ----
  #pragma unroll
  for (int k = 0; k < 4; ++k) {
    const bf16x8 frag = pack4(
        cvt_pk_bf16(FK(f1_[0], k), FK(f1_[1], k)),
        cvt_pk_bf16(FK(f1_[2], k), FK(f1_[3], k)),
        cvt_pk_bf16(FK(f1_[4], k), FK(f1_[5], k)),
        cvt_pk_bf16(FK(f1_[6], k), FK(f1_[7], k)));
    *(bf16x8*)&x_s[g * 1024 + swzj(j4 + k) * 8] = frag;
  }
  __syncthreads();

  // ---- phase 2: c 64..127 ----
  #pragma unroll
  for (int cc = 4; cc < 8; ++cc) {
    const bf16x8 xf = *(const bf16x8*)&x_s[((cc - 4) * 2 + hi) * 1024 + swzj(jl) * 8];
    const int off = cc * 16 + hi * 8;
    const bf16x8 a0 = *(const bf16x8*)&w_s[l31 * WSTRIDE + off];
    const bf16x8 a1 = *(const bf16x8*)&w_s[(32 + l31) * WSTRIDE + off];
    const bf16x8 a2 = *(const bf16x8*)&w_s[(64 + l31) * WSTRIDE + off];
    acc0 = __builtin_amdgcn_mfma_f32_32x32x16_bf16(a0, xf, acc0, 0, 0, 0);
    acc1 = __builtin_amdgcn_mfma_f32_32x32x16_bf16(a1, xf, acc1, 0, 0, 0);
    acc2 = __builtin_amdgcn_mfma_f32_32x32x16_bf16(a2, xf, acc2, 0, 0, 0);
  }

  // ---- q: rows 0..15 (regs 0..7), scaled by log2e, -> B-frag layout ----
  {
    unsigned u0 = cvt_pk_bf16(acc0[0] * LOG2E, acc0[1] * LOG2E);
    unsigned u1 = cvt_pk_bf16(acc0[2] * LOG2E, acc0[3] * LOG2E);
    unsigned u2 = cvt_pk_bf16(acc0[4] * LOG2E, acc0[5] * LOG2E);
    unsigned u3 = cvt_pk_bf16(acc0[6] * LOG2E, acc0[7] * LOG2E);
    perm32swap(u0, u2); perm32swap(u1, u3);
    *(bf16x8*)(qT + ((size_t)b * 4096 + p) * 16 + hi * 8) = pack4(u0, u1, u2, u3);
  }

  // ---- k: rows 16..31 (regs 8..15), pool across lane quads ----
  {
    float pk[8];
    #pragma unroll
    for (int rg = 8; rg < 16; ++rg) {
      float m = acc0[rg];
      m = fmaxf(m, __shfl_xor(m, 1));
      m = fmaxf(m, __shfl_xor(m, 2));
      pk[rg - 8] = m;
    }
    unsigned u0 = cvt_pk_bf16(pk[0], pk[1]), u1 = cvt_pk_bf16(pk[2], pk[3]);
    unsigned u2 = cvt_pk_bf16(pk[4], pk[5]), u3 = cvt_pk_bf16(pk[6], pk[7]);
    perm32swap(u0, u2); perm32swap(u1, u3);
    if ((l31 & 3) == 0)
      *(bf16x8*)(kT + ((size_t)b * 1024 + (p >> 2)) * 16 + hi * 8) =
          pack4(u0, u1, u2, u3);
  }

  // ---- v: pool both tiles -> v_s[ks][c2][16 mm] ----
  {
    float pv1[16], pv2[16];
    #pragma unroll
    for (int rg = 0; rg < 16; ++rg) {
      float m1 = acc1[rg], m2 = acc2[rg];
      m1 = fmaxf(m1, __shfl_xor(m1, 1)); m1 = fmaxf(m1, __shfl_xor(m1, 2));
      m2 = fmaxf(m2, __shfl_xor(m2, 1)); m2 = fmaxf(m2, __shfl_xor(m2, 2));
      pv1[rg] = m1; pv2[rg] = m2;
    }
    if ((l31 & 3) == 0) {
      const int q2p = wid * 8 + (l31 >> 2);      // m within tile, 0..31
      const int ks = q2p >> 4, mm = q2p & 15;
      #pragma unroll
      for (int rg = 0; rg < 16; ++rg) {
        const int c2 = (rg & 3) + 8 * (rg >> 2) + 4 * hi;
        v_s[ks * 1024 + c2 * 16 + mm]        = f2bf(pv1[rg]);
        v_s[ks * 1024 + (32 + c2) * 16 + mm] = f2bf(pv2[rg]);
      }
    }
  }
  __syncthreads();
  *(bf16x8*)(vT + (size_t)b * 65536 + r * 2048 + t * 8) =
      *(const bf16x8*)&v_s[t * 8];
}

// ---------------------------------------------------------------------------
// Kernel 2: flash attention + wo + residual. Block = 128 q (4 waves, no
// split-M), all waves share one m-tile stream. V tiles (4 KB) staged into
// double-buffered XOR-swizzled LDS via reg-staging (issue-early/write-late:
// __syncthreads never drains an in-flight load). K depth-2 in registers.
// ---------------------------------------------------------------------------
#define WOSTRIDE 68   // shorts; 136B row stride

__global__ __launch_bounds__(256) void attn_kernel(
    const short* __restrict__ qT, const short* __restrict__ kT,
    const short* __restrict__ vT, const float* __restrict__ wo,
    const float* __restrict__ x, const float* __restrict__ gamma,
    float* __restrict__ out)
{
  __shared__ short wo_s[128 * WOSTRIDE];   // 17 KB
  __shared__ short v_lds[2 * 2048];        // 8 KB: two 4 KB swizzled V tiles

  const int t = threadIdx.x;
  const int wid = t >> 6, lane = t & 63;
  const int l31 = lane & 31, hi = lane >> 5;

  // XCD-chunked swizzle (512 blocks, 64/XCD): XCD k serves 2 batches
  const int wg = blockIdx.x;                  // 0..511
  const int sw = (wg & 7) * 64 + (wg >> 3);
  const int b = sw >> 5;
  const int p = (sw & 31) * 128 + wid * 32 + l31;

  // ---- stage wo (128x64 fp32) -> bf16 LDS, padded rows ----
  #pragma unroll
  for (int kk = 0; kk < 8; ++kk) {
    const int idx = t + kk * 256;            // 0..2047 float4
    const int row = idx >> 4, c4 = (idx & 15) << 2;
    const float4 f = *(const float4*)(wo + row * 64 + c4);
    const ull v = ((ull)cvt_pk_bf16(f.z, f.w) << 32) | (ull)cvt_pk_bf16(f.x, f.y);
    *(ull*)&wo_s[row * WOSTRIDE + c4] = v;
  }

  const short* kTb = kT + (size_t)b * 1024 * 16;
  const short* vb  = vT + (size_t)b * 65536;
  const bf16x8 qf = *(const bf16x8*)(qT + ((size_t)b * 4096 + p) * 16 + hi * 8);

  // swizzle: physical = logical ^ (((logical>>5)&7)<<4)  (bits 4-6, bijective)
  const int wdst  = (t * 16) ^ (((t >> 1) & 7) << 4);        // write, 16B/thread
  const int rbase = (l31 * 32 + hi * 16) ^ ((l31 & 7) << 4); // read base

  f32x16 z, o0, o1;
  #pragma unroll
  for (int j = 0; j < 16; ++j) { z[j] = 0.f; o0[j] = 0.f; o1[j] = 0.f; }
  float l = 0.f;

  bf16x8 kfA, kfB, vregA, vregB;

#define COMP(S, BUF) do {                                                    \
    f32x16 s = __builtin_amdgcn_mfma_f32_32x32x16_bf16(kf##S, qf, z, 0, 0, 0);\
    const char* vp_ = (const char*)v_lds + (BUF) * 4096 + rbase;             \
    const bf16x8 w00 = *(const bf16x8*)(vp_);                                \
    const bf16x8 w10 = *(const bf16x8*)(vp_ + 1024);                         \
    const bf16x8 w01 = *(const bf16x8*)(vp_ + 2048);                         \
    const bf16x8 w11 = *(const bf16x8*)(vp_ + 3072);                         \
    float pe[16];                                                            \
    _Pragma("unroll")                                                        \
    for (int j = 0; j < 16; ++j) pe[j] = fexp2(s[j]);                        \
    l += ((pe[0]+pe[1])+(pe[2]+pe[3])) + ((pe[4]+pe[5])+(pe[6]+pe[7]))       \
       + ((pe[8]+pe[9])+(pe[10]+pe[11])) + ((pe[12]+pe[13])+(pe[14]+pe[15]));\
    unsigned a0 = cvt_pk_bf16(pe[0], pe[1]),  a1 = cvt_pk_bf16(pe[2], pe[3]);\
    unsigned a2 = cvt_pk_bf16(pe[4], pe[5]),  a3 = cvt_pk_bf16(pe[6], pe[7]);\
    perm32swap(a0, a2); perm32swap(a1, a3);                                  \
    const bf16x8 P0 = pack4(a0, a1, a2, a3);                                 \
    unsigned c0 = cvt_pk_bf16(pe[8], pe[9]),   c1 = cvt_pk_bf16(pe[10], pe[11]);\
    unsigned c2 = cvt_pk_bf16(pe[12], pe[13]), c3 = cvt_pk_bf16(pe[14], pe[15]);\
    perm32swap(c0, c2); perm32swap(c1, c3);                                  \
    const bf16x8 P1 = pack4(c0, c1, c2, c3);                                 \
    __builtin_amdgcn_s_setprio(1);                                           \
    o0 = __builtin_amdgcn_mfma_f32_32x32x16_bf16(w00, P0, o0, 0, 0, 0);      \
    o0 = __builtin_amdgcn_mfma_f32_32x32x16_bf16(w01, P1, o0, 0, 0, 0);      \
    o1 = __builtin_amdgcn_mfma_f32_32x32x16_bf16(w10, P0, o1, 0, 0, 0);      \
    o1 = __builtin_amdgcn_mfma_f32_32x32x16_bf16(w11, P1, o1, 0, 0, 0);      \
    __builtin_amdgcn_s_setprio(0); } while (0)

  // prologue: stage tile 0 into buf0
  vregA = *(const bf16x8*)(vb + t * 8);
  kfA   = *(const bf16x8*)(kTb + (size_t)l31 * 16 + hi * 8);
  *(bf16x8*)((char*)v_lds + wdst) = vregA;
  __syncthreads();

  #pragma unroll 1
  for (int mt = 0; mt < 32; mt += 2) {
    // prefetch tile mt+1 (always exists)
    vregB = *(const bf16x8*)(vb + (size_t)(mt + 1) * 2048 + t * 8);
    kfB   = *(const bf16x8*)(kTb + (size_t)((mt + 1) * 32 + l31) * 16 + hi * 8);
    COMP(A, 0);                                    // tile mt from buf0
    *(bf16x8*)((char*)v_lds + 4096 + wdst) = vregB;  // buf1 (prev readers done)
    __syncthreads();                               // buf1 ready, buf0 free
    if (mt < 30) {
      vregA = *(const bf16x8*)(vb + (size_t)(mt + 2) * 2048 + t * 8);
      kfA   = *(const bf16x8*)(kTb + (size_t)((mt + 2) * 32 + l31) * 16 + hi * 8);
    }
    COMP(B, 1);                                    // tile mt+1 from buf1
    if (mt < 30)
      *(bf16x8*)((char*)v_lds + wdst) = vregA;     // buf0
    __syncthreads();                               // buf0 ready, buf1 free
  }
#undef COMP

  l += __shfl_xor(l, 32);
  const float inv = 1.0f / l;

  float on[32];
  #pragma unroll
  for (int j = 0; j < 16; ++j) { on[j] = o0[j] * inv; on[16 + j] = o1[j] * inv; }

  bf16x8 ofr[4];
  #pragma unroll
  for (int ck = 0; ck < 4; ++ck) {
    const int base = (ck >> 1) * 16 + (ck & 1) * 8;
    unsigned a0 = cvt_pk_bf16(on[base + 0], on[base + 1]);
    unsigned a1 = cvt_pk_bf16(on[base + 2], on[base + 3]);
    unsigned a2 = cvt_pk_bf16(on[base + 4], on[base + 5]);
    unsigned a3 = cvt_pk_bf16(on[base + 6], on[base + 7]);
    perm32swap(a0, a2); perm32swap(a1, a3);
    ofr[ck] = pack4(a0, a1, a2, a3);
  }

  const int q2 = p >> 2, rr = p & 3;
  const int nsp = ((((q2 >> 5) << 1) | (rr >> 1)) << 6) | (((q2 & 31) << 1) | (rr & 1));
  const float g = gamma[0];
  const float* xb = x + (size_t)b * 128 * 4096 + nsp;
  float* ob = out + (size_t)b * 128 * 4096 + nsp;

  #pragma unroll 1
  for (int cot = 0; cot < 4; ++cot) {
    f32x16 acc;
    #pragma unroll
    for (int j = 0; j < 16; ++j) acc[j] = 0.f;
    #pragma unroll
    for (int ck = 0; ck < 4; ++ck) {
      const short* pw = &wo_s[(cot * 32 + l31) * WOSTRIDE + ck * 16 + hi * 8];
      const bf16x8 wf = pack2ull(*(const ull*)pw, *(const ull*)(pw + 4));
      acc = __builtin_amdgcn_mfma_f32_32x32x16_bf16(wf, ofr[ck], acc, 0, 0, 0);
    }
    #pragma unroll
    for (int rg = 0; rg < 16; ++rg) {
      const int co = cot * 32 + (rg & 3) + 8 * (rg >> 2) + 4 * hi;
      ob[(size_t)co * 4096] = g * acc[rg] + xb[(size_t)co * 4096];
    }
  }
}

extern "C" void kernel_launch(void* const* d_in, const int* in_sizes, int n_in,
                              void* d_out, int out_size, void* d_ws, size_t ws_size,
                              hipStream_t stream) {
  const float* x     = (const float*)d_in[0];
  const float* wq    = (const float*)d_in[1];
  const float* wk    = (const float*)d_in[2];
  const float* wv    = (const float*)d_in[3];
  const float* wo    = (const float*)d_in[4];
  const float* gamma = (const float*)d_in[5];
  float* out = (float*)d_out;

  short* ws = (short*)d_ws;
  short* qT = ws;                 // 16*4096*16
  short* kT = ws + 1048576;       // 16*1024*16
  short* vT = ws + 1310720;       // 16*32*2048

  proj_kernel<<<dim3(32, 16), 256, 0, stream>>>(x, wq, wk, wv, qT, kT, vT);
  attn_kernel<<<dim3(512), 256, 0, stream>>>(qT, kT, vT, wo, x, gamma, out);
}